// Round 2
// baseline (282.823 us; speedup 1.0000x reference)
//
#include <hip/hip_runtime.h>
#include <math.h>

#define NPG 500      // nodes per graph
#define DIM 256      // feature dim
#define HID 64       // hidden dim
#define RATIO_NORM 600.0f
#define LPN 8        // lanes per node in k_score (each owns HID/LPN = 8 h)

// ---------------------------------------------------------------- K1: scores
// score[n] = relu(x[n,:] @ Ws1 + bs1) @ Ws2 + bs2
// 8 lanes per node; lane owns 8 hidden units (acc[8] in VGPRs).
// -> 800k threads = 3125 blocks, ~12 waves/SIMD for latency hiding.
__global__ __launch_bounds__(256) void k_score(
    const float* __restrict__ x,
    const float* __restrict__ Ws1,   // [DIM][HID] row-major
    const float* __restrict__ bs1,   // [HID]
    const float* __restrict__ Ws2,   // [HID]
    const float* __restrict__ bs2,   // [1]
    float* __restrict__ score, int N)
{
    int t = blockIdx.x * 256 + threadIdx.x;
    int node = t / LPN;
    int p = t & (LPN - 1);
    int h0 = p * (HID / LPN);                     // 8 hidden units per lane
    int nodec = node < N ? node : (N - 1);
    const float4* xr = reinterpret_cast<const float4*>(x + (size_t)nodec * DIM);

    float4 a0 = *reinterpret_cast<const float4*>(bs1 + h0);
    float4 a1 = *reinterpret_cast<const float4*>(bs1 + h0 + 4);

    for (int k4 = 0; k4 < DIM / 4; ++k4) {
        float4 xv = xr[k4];
        const float* wb = Ws1 + (size_t)(k4 * 4) * HID + h0;
#pragma unroll
        for (int kk = 0; kk < 4; ++kk) {
            float xk = kk == 0 ? xv.x : kk == 1 ? xv.y : kk == 2 ? xv.z : xv.w;
            float4 wa = *reinterpret_cast<const float4*>(wb + kk * HID);
            float4 wc = *reinterpret_cast<const float4*>(wb + kk * HID + 4);
            a0.x = fmaf(xk, wa.x, a0.x);
            a0.y = fmaf(xk, wa.y, a0.y);
            a0.z = fmaf(xk, wa.z, a0.z);
            a0.w = fmaf(xk, wa.w, a0.w);
            a1.x = fmaf(xk, wc.x, a1.x);
            a1.y = fmaf(xk, wc.y, a1.y);
            a1.z = fmaf(xk, wc.z, a1.z);
            a1.w = fmaf(xk, wc.w, a1.w);
        }
    }
    // second layer partial on this lane's 8 h
    float4 w0 = *reinterpret_cast<const float4*>(Ws2 + h0);
    float4 w1 = *reinterpret_cast<const float4*>(Ws2 + h0 + 4);
    float sc = 0.0f;
    sc = fmaf(fmaxf(a0.x, 0.0f), w0.x, sc);
    sc = fmaf(fmaxf(a0.y, 0.0f), w0.y, sc);
    sc = fmaf(fmaxf(a0.z, 0.0f), w0.z, sc);
    sc = fmaf(fmaxf(a0.w, 0.0f), w0.w, sc);
    sc = fmaf(fmaxf(a1.x, 0.0f), w1.x, sc);
    sc = fmaf(fmaxf(a1.y, 0.0f), w1.y, sc);
    sc = fmaf(fmaxf(a1.z, 0.0f), w1.z, sc);
    sc = fmaf(fmaxf(a1.w, 0.0f), w1.w, sc);
    // reduce across the 8 lanes of this node (lanes differ in low 3 bits)
    sc += __shfl_xor(sc, 1, 64);
    sc += __shfl_xor(sc, 2, 64);
    sc += __shfl_xor(sc, 4, 64);
    if (p == 0 && node < N) score[node] = sc + bs2[0];
}

// ------------------------------------------------------------- K2: edge count
__global__ __launch_bounds__(256) void k_edges(
    const int* __restrict__ esrc, const int* __restrict__ edst,
    int* __restrict__ counts, int E, int G)
{
    __shared__ int hist[256];
    for (int i = threadIdx.x; i < G; i += 256) hist[i] = 0;
    __syncthreads();

    int nchunk = E >> 2;
    const int4* s4 = reinterpret_cast<const int4*>(esrc);
    const int4* d4 = reinterpret_cast<const int4*>(edst);
    for (int c = blockIdx.x * 256 + threadIdx.x; c < nchunk; c += gridDim.x * 256) {
        int4 s = s4[c], d = d4[c];
        int g;
        g = s.x / NPG; if (g == d.x / NPG) atomicAdd(&hist[g], 1);
        g = s.y / NPG; if (g == d.y / NPG) atomicAdd(&hist[g], 1);
        g = s.z / NPG; if (g == d.z / NPG) atomicAdd(&hist[g], 1);
        g = s.w / NPG; if (g == d.w / NPG) atomicAdd(&hist[g], 1);
    }
    if (blockIdx.x == 0) {
        for (int e = (nchunk << 2) + threadIdx.x; e < E; e += 256) {
            int g = esrc[e] / NPG;
            if (g == edst[e] / NPG) atomicAdd(&hist[g], 1);
        }
    }
    __syncthreads();
    for (int i = threadIdx.x; i < G; i += 256)
        if (hist[i]) atomicAdd(&counts[i], hist[i]);
}

// ------------------------------------------- K3: per-graph avg + keep_num MLP
__global__ __launch_bounds__(256) void k_keep(
    const float* __restrict__ score,
    const int* __restrict__ counts,
    const float* __restrict__ Wp1,   // [3][HID]
    const float* __restrict__ bp1,   // [HID]
    const float* __restrict__ Wp2,   // [HID]
    const float* __restrict__ bp2,   // [1]
    int* __restrict__ keep_num)
{
    int g = blockIdx.x;
    __shared__ float red[256];
    const float* s = score + (size_t)g * NPG;
    float v = 0.0f;
    for (int i = threadIdx.x; i < NPG; i += 256) v += s[i];
    red[threadIdx.x] = v;
    __syncthreads();
    for (int off = 128; off >= 1; off >>= 1) {
        if (threadIdx.x < off) red[threadIdx.x] += red[threadIdx.x + off];
        __syncthreads();
    }
    if (threadIdx.x < 64) {
        float f0 = (float)NPG / RATIO_NORM;
        float f1 = red[0] / (float)NPG;
        float f2 = (float)counts[g] / (float)(NPG * (NPG - 1));
        int h = threadIdx.x;
        float hv = bp1[h];
        hv = fmaf(f0, Wp1[h], hv);
        hv = fmaf(f1, Wp1[HID + h], hv);
        hv = fmaf(f2, Wp1[2 * HID + h], hv);
        hv = fmaxf(hv, 0.0f) * Wp2[h];
#pragma unroll
        for (int m = 32; m >= 1; m >>= 1) hv += __shfl_xor(hv, m, 64);
        if (h == 0) {
            float z = hv + bp2[0];
            float kr = 1.0f / (1.0f + expf(-z));
            int kn = (int)((float)NPG * kr);
            keep_num[g] = kn < 2 ? 2 : kn;
        }
    }
}

// ---------------------------- K4a: per-graph rank -> mask (float) + gate tanh
__global__ __launch_bounds__(256) void k_rank(
    const float* __restrict__ score,
    const int* __restrict__ keep_num,
    float* __restrict__ out_mask,   // [N] 0.0/1.0
    float* __restrict__ gate)       // [N] tanh(score) or 0
{
    int g = blockIdx.x;
    __shared__ float s[NPG];
    const float* sg = score + (size_t)g * NPG;
    for (int i = threadIdx.x; i < NPG; i += 256) s[i] = sg[i];
    __syncthreads();

    int kn = keep_num[g];
    for (int i = threadIdx.x; i < NPG; i += 256) {
        float si = s[i];
        int rank = 0;
        for (int j = 0; j < NPG; ++j) {
            float sj = s[j];
            rank += (sj > si) || ((sj == si) && (j < i));
        }
        bool keep = rank < kn;
        size_t idx = (size_t)g * NPG + i;
        out_mask[idx] = keep ? 1.0f : 0.0f;
        gate[idx] = keep ? tanhf(si) : 0.0f;
    }
}

// ------------------------------------------ K4b: gated row write (full BW)
// 64 lanes per row (float4 = 1KB/row), 4 rows per block, grid covers all rows.
__global__ __launch_bounds__(256) void k_write(
    const float* __restrict__ x,
    const float* __restrict__ gate,
    float* __restrict__ out_x, int N)
{
    int lane = threadIdx.x & 63;
    int row = blockIdx.x * 4 + (threadIdx.x >> 6);
    if (row >= N) return;
    float gt = gate[row];
    size_t base = (size_t)row * DIM;
    float4* o = reinterpret_cast<float4*>(out_x + base);
    if (gt != 0.0f) {
        const float4* xi = reinterpret_cast<const float4*>(x + base);
        float4 v = xi[lane];
        o[lane] = make_float4(v.x * gt, v.y * gt, v.z * gt, v.w * gt);
    } else {
        o[lane] = make_float4(0.0f, 0.0f, 0.0f, 0.0f);
    }
}

// ---------------------------------------------------------------------- host
extern "C" void kernel_launch(void* const* d_in, const int* in_sizes, int n_in,
                              void* d_out, int out_size, void* d_ws, size_t ws_size,
                              hipStream_t stream)
{
    const float* x   = (const float*)d_in[0];
    const float* Ws1 = (const float*)d_in[1];
    const float* bs1 = (const float*)d_in[2];
    const float* Ws2 = (const float*)d_in[3];
    const float* bs2 = (const float*)d_in[4];
    const float* Wp1 = (const float*)d_in[5];
    const float* bp1 = (const float*)d_in[6];
    const float* Wp2 = (const float*)d_in[7];
    const float* bp2 = (const float*)d_in[8];
    const int* esrc  = (const int*)d_in[9];
    const int* edst  = (const int*)d_in[10];

    int E = in_sizes[9];
    int N = in_sizes[0] / DIM;
    int G = N / NPG;

    float* score = (float*)d_ws;                               // N floats
    float* gate  = score + N;                                  // N floats
    int* counts  = (int*)(gate + N);                           // G ints
    int* keep    = counts + G;                                 // G ints

    float* out_x    = (float*)d_out;
    float* out_mask = out_x + (size_t)N * DIM;

    hipMemsetAsync(counts, 0, G * sizeof(int), stream);
    k_score<<<(N * LPN + 255) / 256, 256, 0, stream>>>(x, Ws1, bs1, Ws2, bs2, score, N);
    k_edges<<<512, 256, 0, stream>>>(esrc, edst, counts, E, G);
    k_keep<<<G, 256, 0, stream>>>(score, counts, Wp1, bp1, Wp2, bp2, keep);
    k_rank<<<G, 256, 0, stream>>>(score, keep, out_mask, gate);
    k_write<<<(N + 3) / 4, 256, 0, stream>>>(x, gate, out_x, N);
}

// Round 3
// 132.212 us; speedup vs baseline: 2.1392x; 2.1392x over previous
//
#include <hip/hip_runtime.h>
#include <math.h>

#define NPG 500      // nodes per graph
#define DIM 256      // feature dim
#define HID 64       // hidden dim
#define RATIO_NORM 600.0f
#define WPB 4        // waves per block in k_score
#define HPW (HID / WPB)   // 16 hidden units per wave

// ---------------------------------------------------------------- K1: scores
// score[n] = relu(x[n,:] @ Ws1 + bs1) @ Ws2 + bs2
// Layout: lane = node (64 nodes/block), wave = 16-wide slice of hidden dim.
// Weight addresses depend only on the wave id -> readfirstlane forces the
// compiler to keep them uniform -> s_load (scalar K$) path, vector pipe
// carries only x. 1563 blocks * 4 waves = ~6.1 waves/SIMD of TLP.
__global__ __launch_bounds__(256) void k_score(
    const float* __restrict__ x,
    const float* __restrict__ Ws1,   // [DIM][HID] row-major
    const float* __restrict__ bs1,   // [HID]
    const float* __restrict__ Ws2,   // [HID]
    const float* __restrict__ bs2,   // [1]
    float* __restrict__ score, int N)
{
    int lane = threadIdx.x & 63;
    int wv   = __builtin_amdgcn_readfirstlane(threadIdx.x >> 6); // uniform
    int node = blockIdx.x * 64 + lane;
    int nodec = node < N ? node : (N - 1);
    int h0 = wv * HPW;

    const float4* xr = reinterpret_cast<const float4*>(x + (size_t)nodec * DIM);
    const float* bs = bs1 + h0;

    float4 a0 = make_float4(bs[0], bs[1], bs[2], bs[3]);
    float4 a1 = make_float4(bs[4], bs[5], bs[6], bs[7]);
    float4 a2 = make_float4(bs[8], bs[9], bs[10], bs[11]);
    float4 a3 = make_float4(bs[12], bs[13], bs[14], bs[15]);

    for (int k4 = 0; k4 < DIM / 4; ++k4) {
        float4 xv = xr[k4];
        const float* wb = Ws1 + (size_t)(k4 * 4) * HID + h0;
#pragma unroll
        for (int kk = 0; kk < 4; ++kk) {
            float xk = kk == 0 ? xv.x : kk == 1 ? xv.y : kk == 2 ? xv.z : xv.w;
            const float* w = wb + kk * HID;   // wave-uniform -> s_load
            a0.x = fmaf(xk, w[0],  a0.x);
            a0.y = fmaf(xk, w[1],  a0.y);
            a0.z = fmaf(xk, w[2],  a0.z);
            a0.w = fmaf(xk, w[3],  a0.w);
            a1.x = fmaf(xk, w[4],  a1.x);
            a1.y = fmaf(xk, w[5],  a1.y);
            a1.z = fmaf(xk, w[6],  a1.z);
            a1.w = fmaf(xk, w[7],  a1.w);
            a2.x = fmaf(xk, w[8],  a2.x);
            a2.y = fmaf(xk, w[9],  a2.y);
            a2.z = fmaf(xk, w[10], a2.z);
            a2.w = fmaf(xk, w[11], a2.w);
            a3.x = fmaf(xk, w[12], a3.x);
            a3.y = fmaf(xk, w[13], a3.y);
            a3.z = fmaf(xk, w[14], a3.z);
            a3.w = fmaf(xk, w[15], a3.w);
        }
    }

    // second layer partial on this wave's 16 h (Ws2 reads also uniform)
    const float* w2 = Ws2 + h0;
    float p = 0.0f;
    p = fmaf(fmaxf(a0.x, 0.0f), w2[0],  p);
    p = fmaf(fmaxf(a0.y, 0.0f), w2[1],  p);
    p = fmaf(fmaxf(a0.z, 0.0f), w2[2],  p);
    p = fmaf(fmaxf(a0.w, 0.0f), w2[3],  p);
    p = fmaf(fmaxf(a1.x, 0.0f), w2[4],  p);
    p = fmaf(fmaxf(a1.y, 0.0f), w2[5],  p);
    p = fmaf(fmaxf(a1.z, 0.0f), w2[6],  p);
    p = fmaf(fmaxf(a1.w, 0.0f), w2[7],  p);
    p = fmaf(fmaxf(a2.x, 0.0f), w2[8],  p);
    p = fmaf(fmaxf(a2.y, 0.0f), w2[9],  p);
    p = fmaf(fmaxf(a2.z, 0.0f), w2[10], p);
    p = fmaf(fmaxf(a2.w, 0.0f), w2[11], p);
    p = fmaf(fmaxf(a3.x, 0.0f), w2[12], p);
    p = fmaf(fmaxf(a3.y, 0.0f), w2[13], p);
    p = fmaf(fmaxf(a3.z, 0.0f), w2[14], p);
    p = fmaf(fmaxf(a3.w, 0.0f), w2[15], p);

    __shared__ float part[WPB][64];
    part[wv][lane] = p;
    __syncthreads();
    if (wv == 0 && node < N) {
        float sc = part[0][lane] + part[1][lane] + part[2][lane] + part[3][lane]
                 + bs2[0];
        score[node] = sc;
    }
}

// ------------------------------------------------------------- K2: edge count
__global__ __launch_bounds__(256) void k_edges(
    const int* __restrict__ esrc, const int* __restrict__ edst,
    int* __restrict__ counts, int E, int G)
{
    __shared__ int hist[256];
    for (int i = threadIdx.x; i < G; i += 256) hist[i] = 0;
    __syncthreads();

    int nchunk = E >> 2;
    const int4* s4 = reinterpret_cast<const int4*>(esrc);
    const int4* d4 = reinterpret_cast<const int4*>(edst);
    for (int c = blockIdx.x * 256 + threadIdx.x; c < nchunk; c += gridDim.x * 256) {
        int4 s = s4[c], d = d4[c];
        int g;
        g = s.x / NPG; if (g == d.x / NPG) atomicAdd(&hist[g], 1);
        g = s.y / NPG; if (g == d.y / NPG) atomicAdd(&hist[g], 1);
        g = s.z / NPG; if (g == d.z / NPG) atomicAdd(&hist[g], 1);
        g = s.w / NPG; if (g == d.w / NPG) atomicAdd(&hist[g], 1);
    }
    if (blockIdx.x == 0) {
        for (int e = (nchunk << 2) + threadIdx.x; e < E; e += 256) {
            int g = esrc[e] / NPG;
            if (g == edst[e] / NPG) atomicAdd(&hist[g], 1);
        }
    }
    __syncthreads();
    for (int i = threadIdx.x; i < G; i += 256)
        if (hist[i]) atomicAdd(&counts[i], hist[i]);
}

// ------------------------------------------- K3: per-graph avg + keep_num MLP
__global__ __launch_bounds__(256) void k_keep(
    const float* __restrict__ score,
    const int* __restrict__ counts,
    const float* __restrict__ Wp1,   // [3][HID]
    const float* __restrict__ bp1,   // [HID]
    const float* __restrict__ Wp2,   // [HID]
    const float* __restrict__ bp2,   // [1]
    int* __restrict__ keep_num)
{
    int g = blockIdx.x;
    __shared__ float red[256];
    const float* s = score + (size_t)g * NPG;
    float v = 0.0f;
    for (int i = threadIdx.x; i < NPG; i += 256) v += s[i];
    red[threadIdx.x] = v;
    __syncthreads();
    for (int off = 128; off >= 1; off >>= 1) {
        if (threadIdx.x < off) red[threadIdx.x] += red[threadIdx.x + off];
        __syncthreads();
    }
    if (threadIdx.x < 64) {
        float f0 = (float)NPG / RATIO_NORM;
        float f1 = red[0] / (float)NPG;
        float f2 = (float)counts[g] / (float)(NPG * (NPG - 1));
        int h = threadIdx.x;
        float hv = bp1[h];
        hv = fmaf(f0, Wp1[h], hv);
        hv = fmaf(f1, Wp1[HID + h], hv);
        hv = fmaf(f2, Wp1[2 * HID + h], hv);
        hv = fmaxf(hv, 0.0f) * Wp2[h];
#pragma unroll
        for (int m = 32; m >= 1; m >>= 1) hv += __shfl_xor(hv, m, 64);
        if (h == 0) {
            float z = hv + bp2[0];
            float kr = 1.0f / (1.0f + expf(-z));
            int kn = (int)((float)NPG * kr);
            keep_num[g] = kn < 2 ? 2 : kn;
        }
    }
}

// ---------------------------- K4a: per-graph rank -> mask (float) + gate tanh
__global__ __launch_bounds__(256) void k_rank(
    const float* __restrict__ score,
    const int* __restrict__ keep_num,
    float* __restrict__ out_mask,   // [N] 0.0/1.0
    float* __restrict__ gate)       // [N] tanh(score) or 0
{
    int g = blockIdx.x;
    __shared__ float s[NPG];
    const float* sg = score + (size_t)g * NPG;
    for (int i = threadIdx.x; i < NPG; i += 256) s[i] = sg[i];
    __syncthreads();

    int kn = keep_num[g];
    for (int i = threadIdx.x; i < NPG; i += 256) {
        float si = s[i];
        int rank = 0;
        for (int j = 0; j < NPG; ++j) {
            float sj = s[j];
            rank += (sj > si) || ((sj == si) && (j < i));
        }
        bool keep = rank < kn;
        size_t idx = (size_t)g * NPG + i;
        out_mask[idx] = keep ? 1.0f : 0.0f;
        gate[idx] = keep ? tanhf(si) : 0.0f;
    }
}

// ------------------------------------------ K4b: gated row write (full BW)
__global__ __launch_bounds__(256) void k_write(
    const float* __restrict__ x,
    const float* __restrict__ gate,
    float* __restrict__ out_x, int N)
{
    int lane = threadIdx.x & 63;
    int row = blockIdx.x * 4 + (threadIdx.x >> 6);
    if (row >= N) return;
    float gt = gate[row];
    size_t base = (size_t)row * DIM;
    float4* o = reinterpret_cast<float4*>(out_x + base);
    if (gt != 0.0f) {
        const float4* xi = reinterpret_cast<const float4*>(x + base);
        float4 v = xi[lane];
        o[lane] = make_float4(v.x * gt, v.y * gt, v.z * gt, v.w * gt);
    } else {
        o[lane] = make_float4(0.0f, 0.0f, 0.0f, 0.0f);
    }
}

// ---------------------------------------------------------------------- host
extern "C" void kernel_launch(void* const* d_in, const int* in_sizes, int n_in,
                              void* d_out, int out_size, void* d_ws, size_t ws_size,
                              hipStream_t stream)
{
    const float* x   = (const float*)d_in[0];
    const float* Ws1 = (const float*)d_in[1];
    const float* bs1 = (const float*)d_in[2];
    const float* Ws2 = (const float*)d_in[3];
    const float* bs2 = (const float*)d_in[4];
    const float* Wp1 = (const float*)d_in[5];
    const float* bp1 = (const float*)d_in[6];
    const float* Wp2 = (const float*)d_in[7];
    const float* bp2 = (const float*)d_in[8];
    const int* esrc  = (const int*)d_in[9];
    const int* edst  = (const int*)d_in[10];

    int E = in_sizes[9];
    int N = in_sizes[0] / DIM;
    int G = N / NPG;

    float* score = (float*)d_ws;                               // N floats
    float* gate  = score + N;                                  // N floats
    int* counts  = (int*)(gate + N);                           // G ints
    int* keep    = counts + G;                                 // G ints

    float* out_x    = (float*)d_out;
    float* out_mask = out_x + (size_t)N * DIM;

    hipMemsetAsync(counts, 0, G * sizeof(int), stream);
    k_score<<<(N + 63) / 64, 256, 0, stream>>>(x, Ws1, bs1, Ws2, bs2, score, N);
    k_edges<<<512, 256, 0, stream>>>(esrc, edst, counts, E, G);
    k_keep<<<G, 256, 0, stream>>>(score, counts, Wp1, bp1, Wp2, bp2, keep);
    k_rank<<<G, 256, 0, stream>>>(score, keep, out_mask, gate);
    k_write<<<(N + 3) / 4, 256, 0, stream>>>(x, gate, out_x, N);
}